// Round 4
// baseline (158.243 us; speedup 1.0000x reference)
//
#include <hip/hip_runtime.h>
#include <hip/hip_bf16.h>

// B=4, S=4096, D=2048, H=16, dh=128, R=4, WIN=128, Cs=1024, ws=3968.
// Chunks 992..1023 are the only ones with live attention; chunks <=991 collapse
// to v[:,0,:]. Resize rows 0..3965 per batch broadcast the base chunk row.
//
// Structure (4 dispatches, no atomics, no memset):
//   qkv_kernel  : split-K fused f32->bf16 staging GEMM -> f32 PARTIAL slices
//                 (Q: 2 slices of K=1024; K/V: 4 slices of K=512), plain stores
//   attn_kernel : sums QKV partials during LDS staging, 32x128 masked softmax
//   o_kernel    : split-K (4) O-projection -> 4 Yo partial slices
//   resize_kernel: sums Yo partials, clamped lerp upsample -> d_out

typedef __attribute__((ext_vector_type(8))) short short8;
typedef __attribute__((ext_vector_type(4))) float f32x4;

#define LDP 72        // LDS row stride in bf16 (144 B: 16B-aligned, low conflict)

#define QP_STRIDE  (128 * 2048)   // floats per Q partial slice
#define KV_STRIDE  (512 * 2048)   // floats per K/V partial slice
#define YO_STRIDE  (132 * 2048)   // floats per Yo partial slice

__device__ __forceinline__ unsigned short f2bf(float f){
  unsigned int x = __float_as_uint(f);
  return (unsigned short)((x + 0x7fffu + ((x >> 16) & 1u)) >> 16);
}
__device__ __forceinline__ unsigned int pk2(float lo, float hi){
  return ((unsigned int)f2bf(hi) << 16) | (unsigned int)f2bf(lo);
}
__device__ __forceinline__ short8 cvt8(float4 x, float4 y){
  union { unsigned int u[4]; short8 s; } r;
  r.u[0] = pk2(x.x, x.y); r.u[1] = pk2(x.z, x.w);
  r.u[2] = pk2(y.x, y.y); r.u[3] = pk2(y.z, y.w);
  return r.s;
}

// A-operand loaders. AMODE: 0 = bf16 rows (Ao), 1 = f32 window rows (K/V),
// 2 = mean of 4 consecutive f32 input rows (Q chunk means).
template<int AMODE>
__device__ __forceinline__ short8 load_a(const void* A, int ra, int kc){
  if constexpr (AMODE == 0){
    return *(const short8*)((const unsigned short*)A + (size_t)ra * 2048 + kc);
  } else if constexpr (AMODE == 1){
    const float* p = (const float*)A + ((size_t)(ra >> 7) * 4096 + 3968 + (ra & 127)) * 2048 + kc;
    return cvt8(*(const float4*)p, *(const float4*)(p + 4));
  } else {
    const float* p = (const float*)A + ((size_t)(ra >> 5) * 4096 + 3968 + 4 * (ra & 31)) * 2048 + kc;
    float4 x0 = *(const float4*)(p);
    float4 x1 = *(const float4*)(p + 2048);
    float4 x2 = *(const float4*)(p + 4096);
    float4 x3 = *(const float4*)(p + 6144);
    float4 y0 = *(const float4*)(p + 4);
    float4 y1 = *(const float4*)(p + 2052);
    float4 y2 = *(const float4*)(p + 4100);
    float4 y3 = *(const float4*)(p + 6148);
    float4 xm, ym;
    xm.x = 0.25f * (x0.x + x1.x + x2.x + x3.x);
    xm.y = 0.25f * (x0.y + x1.y + x2.y + x3.y);
    xm.z = 0.25f * (x0.z + x1.z + x2.z + x3.z);
    xm.w = 0.25f * (x0.w + x1.w + x2.w + x3.w);
    ym.x = 0.25f * (y0.x + y1.x + y2.x + y3.x);
    ym.y = 0.25f * (y0.y + y1.y + y2.y + y3.y);
    ym.z = 0.25f * (y0.z + y1.z + y2.z + y3.z);
    ym.w = 0.25f * (y0.w + y1.w + y2.w + y3.w);
    return cvt8(xm, ym);
  }
}

__device__ __forceinline__ short8 load_b(const float* W, int rb, int kc){
  const float* p = W + (size_t)rb * 2048 + kc;
  return cvt8(*(const float4*)p, *(const float4*)(p + 4));
}

// ---- split-K GEMM slice: Cp[row0..+127, n0..+127] = A[., kbase..]@W^T over
// nsteps BK=64 tiles. 128x128 tile, 4 waves, 16x16x32 bf16 MFMA, reg prefetch
// + LDS double buffer, plain f32 stores.
template<int AMODE>
__device__ __forceinline__ void gemm_body(
    const void* A, const float* W, float* Cp,
    int M, int mt, int nt, int kbase, int nsteps,
    unsigned short* As0, unsigned short* As1,
    unsigned short* Bs0, unsigned short* Bs1)
{
  const int tid  = threadIdx.x;
  const int lane = tid & 63;
  const int wid  = tid >> 6;
  const int wr = wid >> 1, wc = wid & 1;
  const int row0 = mt * 128, n0 = nt * 128;

  const int srow = wid * 8 + (lane >> 3);   // staging row within each 32-row chunk
  const int scol = (lane & 7) * 8;          // staging col (8 bf16 = 16B)

  f32x4 acc[4][4] = {};

  // prologue: stage K-tile 0
  {
    short8 pa[4], pb[4];
    #pragma unroll
    for (int c = 0; c < 4; ++c){
      int r = c * 32 + srow;
      int ra = row0 + r; if (ra > M - 1) ra = M - 1;
      pa[c] = load_a<AMODE>(A, ra, kbase + scol);
      pb[c] = load_b(W, n0 + r, kbase + scol);
    }
    #pragma unroll
    for (int c = 0; c < 4; ++c){
      int r = c * 32 + srow;
      *(short8*)&As0[r * LDP + scol] = pa[c];
      *(short8*)&Bs0[r * LDP + scol] = pb[c];
    }
  }
  __syncthreads();

  const unsigned short* Asr = As0; const unsigned short* Bsr = Bs0;
  unsigned short* Asd = As1; unsigned short* Bsd = Bs1;

  for (int t = 0; t < nsteps; ++t){
    short8 na[4], nb[4];
    const bool pf = (t + 1) < nsteps;
    if (pf){
      const int k0 = kbase + (t + 1) * 64;
      #pragma unroll
      for (int c = 0; c < 4; ++c){
        int r = c * 32 + srow;
        int ra = row0 + r; if (ra > M - 1) ra = M - 1;
        na[c] = load_a<AMODE>(A, ra, k0 + scol);
        nb[c] = load_b(W, n0 + r, k0 + scol);
      }
    }
    #pragma unroll
    for (int ks = 0; ks < 2; ++ks){
      short8 av[4], bv[4];
      #pragma unroll
      for (int f = 0; f < 4; ++f){
        av[f] = *(const short8*)&Asr[(wr * 64 + f * 16 + (lane & 15)) * LDP + ks * 32 + (lane >> 4) * 8];
        bv[f] = *(const short8*)&Bsr[(wc * 64 + f * 16 + (lane & 15)) * LDP + ks * 32 + (lane >> 4) * 8];
      }
      #pragma unroll
      for (int fm = 0; fm < 4; ++fm)
        #pragma unroll
        for (int fn = 0; fn < 4; ++fn)
          acc[fm][fn] = __builtin_amdgcn_mfma_f32_16x16x32_bf16(av[fm], bv[fn], acc[fm][fn], 0, 0, 0);
    }
    if (pf){
      #pragma unroll
      for (int c = 0; c < 4; ++c){
        int r = c * 32 + srow;
        *(short8*)&Asd[r * LDP + scol] = na[c];
        *(short8*)&Bsd[r * LDP + scol] = nb[c];
      }
    }
    __syncthreads();
    const unsigned short* ta = Asr; Asr = Asd; Asd = (unsigned short*)ta;
    const unsigned short* tb = Bsr; Bsr = Bsd; Bsd = (unsigned short*)tb;
  }

  // epilogue: C/D layout col=lane&15, row=(lane>>4)*4+reg; plain f32 stores
  #pragma unroll
  for (int fm = 0; fm < 4; ++fm){
    #pragma unroll
    for (int fn = 0; fn < 4; ++fn){
      const int col = n0 + wc * 64 + fn * 16 + (lane & 15);
      #pragma unroll
      for (int r = 0; r < 4; ++r){
        const int row = row0 + wr * 64 + fm * 16 + (lane >> 4) * 4 + r;
        if (row < M)
          Cp[(size_t)row * 2048 + col] = acc[fm][fn][r];
      }
    }
  }
}

__global__ __launch_bounds__(256, 2) void qkv_kernel(
    const float* __restrict__ inp,
    const float* __restrict__ Wq, const float* __restrict__ Wk, const float* __restrict__ Wv,
    float* __restrict__ Qp, float* __restrict__ Kp, float* __restrict__ Vp)
{
  __shared__ __align__(16) unsigned short As[2][128 * LDP];
  __shared__ __align__(16) unsigned short Bs[2][128 * LDP];
  const int gy = blockIdx.y, ksp = blockIdx.z;
  if (gy == 0){
    if (ksp >= 2) return;   // Q: 2 slices of K=1024 (16 steps)
    gemm_body<2>(inp, Wq, Qp + (size_t)ksp * QP_STRIDE,
                 128, 0, blockIdx.x, ksp * 1024, 16, As[0], As[1], Bs[0], Bs[1]);
  } else if (gy < 5){
    gemm_body<1>(inp, Wk, Kp + (size_t)ksp * KV_STRIDE,
                 512, gy - 1, blockIdx.x, ksp * 512, 8, As[0], As[1], Bs[0], Bs[1]);
  } else {
    gemm_body<1>(inp, Wv, Vp + (size_t)ksp * KV_STRIDE,
                 512, gy - 5, blockIdx.x, ksp * 512, 8, As[0], As[1], Bs[0], Bs[1]);
  }
}

__global__ __launch_bounds__(256, 2) void o_kernel(
    const unsigned short* __restrict__ Ao, const float* __restrict__ Wo,
    float* __restrict__ Yop)
{
  __shared__ __align__(16) unsigned short As[2][128 * LDP];
  __shared__ __align__(16) unsigned short Bs[2][128 * LDP];
  gemm_body<0>(Ao, Wo, Yop + (size_t)blockIdx.z * YO_STRIDE,
               132, blockIdx.y, blockIdx.x, blockIdx.z * 512, 8,
               As[0], As[1], Bs[0], Bs[1]);
}

// ---------------- attention: chunks 992..1023 only, per (b,h) block ----------------
// Sums the split-K partials of Q (2) and K/V (4) during staging.
__global__ __launch_bounds__(256) void attn_kernel(
    const float* __restrict__ Qp, const float* __restrict__ Kp,
    const float* __restrict__ Vp, const int* __restrict__ amask,
    unsigned short* __restrict__ Ao)
{
  const int b = blockIdx.x >> 4;
  const int h = blockIdx.x & 15;
  __shared__ float Qs[32][129];
  __shared__ unsigned int Ks[128][65];
  __shared__ unsigned int Vs[128][65];
  __shared__ float Wt[32][132];
  __shared__ float msk[128];
  const int tid = threadIdx.x;

  for (int i = tid; i < 32 * 128; i += 256){
    int cq = i >> 7, d = i & 127;
    size_t off = (size_t)(b * 32 + cq) * 2048 + h * 128 + d;
    Qs[cq][d] = Qp[off] + Qp[off + QP_STRIDE];
  }
  for (int i = tid; i < 128 * 64; i += 256){
    int j = i >> 6, du = i & 63;
    size_t off = (size_t)(b * 128 + j) * 2048 + h * 128 + du * 2;
    float2 k0 = *(const float2*)(Kp + off);
    float2 k1 = *(const float2*)(Kp + off + KV_STRIDE);
    float2 k2 = *(const float2*)(Kp + off + 2 * KV_STRIDE);
    float2 k3 = *(const float2*)(Kp + off + 3 * KV_STRIDE);
    float2 v0 = *(const float2*)(Vp + off);
    float2 v1 = *(const float2*)(Vp + off + KV_STRIDE);
    float2 v2 = *(const float2*)(Vp + off + 2 * KV_STRIDE);
    float2 v3 = *(const float2*)(Vp + off + 3 * KV_STRIDE);
    Ks[j][du] = pk2(k0.x + k1.x + k2.x + k3.x, k0.y + k1.y + k2.y + k3.y);
    Vs[j][du] = pk2(v0.x + v1.x + v2.x + v3.x, v0.y + v1.y + v2.y + v3.y);
  }
  if (tid < 128){
    msk[tid] = (amask[b * 4096 + 3968 + tid] != 0) ? 1.f : 0.f;
    // Ao base row (chunks 0..991 collapse to v[:,0,:]); mask[b,3968]==1 here
    size_t off = (size_t)(b * 128) * 2048 + h * 128 + tid;
    Ao[(size_t)(b * 33) * 2048 + h * 128 + tid] =
        f2bf(Vp[off] + Vp[off + KV_STRIDE] + Vp[off + 2 * KV_STRIDE] + Vp[off + 3 * KV_STRIDE]);
  }
  __syncthreads();

  const int cq = tid >> 3, jg = tid & 7;
  const int jmax = 4 * cq + 3;   // causal: j <= 4*cq+3 for chunk 992+cq
  const float scale = 0.088388347648318447f; // 1/sqrt(128)

  float s[16];
  {
    float sacc[16];
    #pragma unroll
    for (int jj = 0; jj < 16; ++jj) sacc[jj] = 0.f;
    for (int du = 0; du < 64; ++du){
      float q0 = Qs[cq][2 * du], q1 = Qs[cq][2 * du + 1];
      #pragma unroll
      for (int jj = 0; jj < 16; ++jj){
        unsigned int u = Ks[jg * 16 + jj][du];
        sacc[jj] += q0 * __uint_as_float(u << 16) + q1 * __uint_as_float(u & 0xffff0000u);
      }
    }
    #pragma unroll
    for (int jj = 0; jj < 16; ++jj){
      int j = jg * 16 + jj;
      bool ok = (j <= jmax) && (msk[j] > 0.5f);
      s[jj] = ok ? sacc[jj] * scale : -1e9f;
    }
  }
  float m = s[0];
  #pragma unroll
  for (int jj = 1; jj < 16; ++jj) m = fmaxf(m, s[jj]);
  #pragma unroll
  for (int off = 1; off < 8; off <<= 1) m = fmaxf(m, __shfl_xor(m, off, 8));
  float sum = 0.f;
  #pragma unroll
  for (int jj = 0; jj < 16; ++jj){ s[jj] = expf(s[jj] - m); sum += s[jj]; }
  #pragma unroll
  for (int off = 1; off < 8; off <<= 1) sum += __shfl_xor(sum, off, 8);
  const float inv = 1.f / sum;
  #pragma unroll
  for (int jj = 0; jj < 16; ++jj) Wt[cq][jg * 16 + jj] = s[jj] * inv;
  __syncthreads();

  const int dg = tid & 7;
  float o[16];
  #pragma unroll
  for (int e = 0; e < 16; ++e) o[e] = 0.f;
  for (int j = 0; j < 128; ++j){
    float w = Wt[cq][j];
    #pragma unroll
    for (int du = 0; du < 8; ++du){
      unsigned int u = Vs[j][dg * 8 + du];
      o[2 * du]     += w * __uint_as_float(u << 16);
      o[2 * du + 1] += w * __uint_as_float(u & 0xffff0000u);
    }
  }
  unsigned short* dst = Ao + (size_t)(b * 33 + 1 + cq) * 2048 + h * 128 + dg * 16;
  #pragma unroll
  for (int e = 0; e < 16; ++e) dst[e] = f2bf(o[e]);
}

// -------- resize: sum Yo partials, linear upsample Cs=1024 -> S=4096 --------
__global__ __launch_bounds__(256) void resize_kernel(
    const float* __restrict__ Yop, float* __restrict__ out)
{
  const int rowid = blockIdx.x;       // b*4096 + i
  const int b = rowid >> 12;
  const int i = rowid & 4095;
  float c  = i * 0.25f - 0.375f;
  float fl = floorf(c);
  int   j0 = (int)fl;
  float f  = c - fl;
  int   j1 = j0 + 1;
  j0 = max(0, min(j0, 1023));
  j1 = max(0, min(j1, 1023));
  const int ri0 = b * 33 + (j0 <= 991 ? 0 : j0 - 991);
  const int ri1 = b * 33 + (j1 <= 991 ? 0 : j1 - 991);
  const float* r0 = Yop + (size_t)ri0 * 2048;
  const float* r1 = Yop + (size_t)ri1 * 2048;
  float* op = out + (size_t)rowid * 2048;
  const int t = threadIdx.x;
  const bool same = (ri0 == ri1);
  #pragma unroll
  for (int q = 0; q < 2; ++q){
    int d = q * 1024 + t * 4;
    float4 a0 = *(const float4*)(r0 + d);
    float4 a1 = *(const float4*)(r0 + d + YO_STRIDE);
    float4 a2 = *(const float4*)(r0 + d + 2 * YO_STRIDE);
    float4 a3 = *(const float4*)(r0 + d + 3 * YO_STRIDE);
    float4 a;
    a.x = a0.x + a1.x + a2.x + a3.x;
    a.y = a0.y + a1.y + a2.y + a3.y;
    a.z = a0.z + a1.z + a2.z + a3.z;
    a.w = a0.w + a1.w + a2.w + a3.w;
    float4 o = a;
    if (!same){
      float4 b0 = *(const float4*)(r1 + d);
      float4 b1 = *(const float4*)(r1 + d + YO_STRIDE);
      float4 b2 = *(const float4*)(r1 + d + 2 * YO_STRIDE);
      float4 b3 = *(const float4*)(r1 + d + 3 * YO_STRIDE);
      float4 bb;
      bb.x = b0.x + b1.x + b2.x + b3.x;
      bb.y = b0.y + b1.y + b2.y + b3.y;
      bb.z = b0.z + b1.z + b2.z + b3.z;
      bb.w = b0.w + b1.w + b2.w + b3.w;
      o.x = a.x + f * (bb.x - a.x);
      o.y = a.y + f * (bb.y - a.y);
      o.z = a.z + f * (bb.z - a.z);
      o.w = a.w + f * (bb.w - a.w);
    }
    *(float4*)(op + d) = o;
  }
}

extern "C" void kernel_launch(void* const* d_in, const int* in_sizes, int n_in,
                              void* d_out, int out_size, void* d_ws, size_t ws_size,
                              hipStream_t stream)
{
  const float* inp   = (const float*)d_in[0];
  const int*   amask = (const int*)d_in[1];
  const float* Wq = (const float*)d_in[2];
  const float* Wk = (const float*)d_in[3];
  const float* Wv = (const float*)d_in[4];
  const float* Wo = (const float*)d_in[5];
  float* out = (float*)d_out;

  char* ws = (char*)d_ws;
  float*          Qp  = (float*)(ws);                      // 2 x [128x2048] f32 partials
  float*          Kp  = (float*)(ws + 2097152);            // 4 x [512x2048] f32 partials
  float*          Vp  = (float*)(ws + 18874368);           // 4 x [512x2048] f32 partials
  float*          Yop = (float*)(ws + 35651584);           // 4 x [132x2048] f32 partials
  unsigned short* Ao  = (unsigned short*)(ws + 39976960);  // 132 x 2048 bf16

  qkv_kernel<<<dim3(16, 9, 4), 256, 0, stream>>>(inp, Wq, Wk, Wv, Qp, Kp, Vp);
  attn_kernel<<<64, 256, 0, stream>>>(Qp, Kp, Vp, amask, Ao);
  o_kernel<<<dim3(16, 2, 4), 256, 0, stream>>>(Ao, Wo, Yop);
  resize_kernel<<<16384, 256, 0, stream>>>(Yop, out);
}

// Round 6
// 117.506 us; speedup vs baseline: 1.3467x; 1.3467x over previous
//
#include <hip/hip_runtime.h>
#include <hip/hip_bf16.h>

// B=4, S=4096, D=2048, H=16, dh=128, R=4, WIN=128, Cs=1024, ws=3968.
// Chunks 992..1023 are the only ones with live attention; chunks <=991 collapse
// to v[:,0,:]. Resize rows 0..3965 per batch broadcast the base chunk row.
//
// Structure (5 dispatches):
//   prep_kernel  : window rows -> bf16 (Awx), Q chunk-means -> bf16 (Aq)
//   qkv_kernel   : split-K GEMM (A bf16 staged, W f32->bf16 fused) -> f32 partials
//                  Q: 2 slices of K=1024; K/V: 4 slices of K=512. 128x64 tile,
//                  single-LDS-buffer + register prefetch, 4 blocks/CU.
//   attn_kernel  : sums QKV partials during LDS staging, 32x128 masked softmax
//   o_kernel     : split-K (4) O-projection -> 4 Yo partial slices
//   resize_kernel: sums Yo partials, clamped lerp upsample -> d_out

typedef __attribute__((ext_vector_type(8))) short short8;
typedef __attribute__((ext_vector_type(4))) short s16x4;
typedef __attribute__((ext_vector_type(4))) float f32x4;

#define LDP 72        // LDS row stride in bf16 (144 B)

#define QP_STRIDE  (128 * 2048)   // floats per Q partial slice
#define KV_STRIDE  (512 * 2048)   // floats per K/V partial slice
#define YO_STRIDE  (132 * 2048)   // floats per Yo partial slice

__device__ __forceinline__ unsigned short f2bf(float f){
  unsigned int x = __float_as_uint(f);
  return (unsigned short)((x + 0x7fffu + ((x >> 16) & 1u)) >> 16);
}
__device__ __forceinline__ unsigned int pk2(float lo, float hi){
  return ((unsigned int)f2bf(hi) << 16) | (unsigned int)f2bf(lo);
}
__device__ __forceinline__ s16x4 cvt4(float4 v){
  union { __hip_bfloat162 h[2]; s16x4 s; } r;
  float2 a; a.x = v.x; a.y = v.y;
  float2 b; b.x = v.z; b.y = v.w;
  r.h[0] = __float22bfloat162_rn(a);
  r.h[1] = __float22bfloat162_rn(b);
  return r.s;
}
__device__ __forceinline__ short8 cvt8(float4 x, float4 y){
  union { s16x4 h[2]; short8 s; } r;
  r.h[0] = cvt4(x); r.h[1] = cvt4(y);
  return r.s;
}

// ---------- prep: window f32->bf16 + Q chunk-means f32->bf16 ----------
__global__ __launch_bounds__(256) void prep_kernel(
    const float* __restrict__ inp,
    unsigned short* __restrict__ Awx, unsigned short* __restrict__ Aq)
{
  const int idx = blockIdx.x * 256 + threadIdx.x;
  if (blockIdx.y == 0){
    // window: 4*128*2048 elems, 8 per thread
    const int b = idx >> 15, rem = idx & 32767;
    const int j = rem >> 8, d8 = (rem & 255) * 8;
    const float* p = inp + ((size_t)b * 4096 + 3968 + j) * 2048 + d8;
    *(short8*)&Awx[((size_t)b * 128 + j) * 2048 + d8] =
        cvt8(*(const float4*)p, *(const float4*)(p + 4));
  } else {
    // chunk means for chunks 992..1023: 4*32*2048 elems, 8 per thread
    if (idx >= 32768) return;
    const int b = idx >> 13, rem = idx & 8191;
    const int c = rem >> 8, d8 = (rem & 255) * 8;
    const float* p = inp + ((size_t)b * 4096 + 3968 + 4 * c) * 2048 + d8;
    float4 x0 = *(const float4*)(p);
    float4 x1 = *(const float4*)(p + 2048);
    float4 x2 = *(const float4*)(p + 4096);
    float4 x3 = *(const float4*)(p + 6144);
    float4 y0 = *(const float4*)(p + 4);
    float4 y1 = *(const float4*)(p + 2052);
    float4 y2 = *(const float4*)(p + 4100);
    float4 y3 = *(const float4*)(p + 6148);
    float4 xm, ym;
    xm.x = 0.25f * (x0.x + x1.x + x2.x + x3.x);
    xm.y = 0.25f * (x0.y + x1.y + x2.y + x3.y);
    xm.z = 0.25f * (x0.z + x1.z + x2.z + x3.z);
    xm.w = 0.25f * (x0.w + x1.w + x2.w + x3.w);
    ym.x = 0.25f * (y0.x + y1.x + y2.x + y3.x);
    ym.y = 0.25f * (y0.y + y1.y + y2.y + y3.y);
    ym.z = 0.25f * (y0.z + y1.z + y2.z + y3.z);
    ym.w = 0.25f * (y0.w + y1.w + y2.w + y3.w);
    *(short8*)&Aq[((size_t)b * 32 + c) * 2048 + d8] = cvt8(xm, ym);
  }
}

// ---- split-K GEMM slice: Cp[row0..+127, n0..+63] = A[.,kbase..]@W^T over
// nsteps BK=64 tiles. 128x64 tile, 4 waves (2x2 of 64x32), 16x16x32 bf16 MFMA,
// register prefetch + SINGLE LDS buffer (2 barriers/iter), plain f32 stores.
__device__ __forceinline__ void gemm_body(
    const unsigned short* __restrict__ A, const float* __restrict__ W,
    float* __restrict__ Cp,
    int M, int row0, int n0, int kbase, int nsteps,
    unsigned short* As, unsigned short* Bs)
{
  const int tid  = threadIdx.x;
  const int lane = tid & 63;
  const int wid  = tid >> 6;
  const int wr = wid >> 1, wc = wid & 1;

  const int arow = tid >> 3;          // 0..31 (A staging row within 32-row chunk)
  const int acol = (tid & 7) * 8;     // A staging col (8 bf16 = 16B)
  const int brow = tid >> 4;          // 0..15 (B staging row within 16-row chunk)
  const int bcol = (tid & 15) * 4;    // B staging col (4 f32 = 16B read, 8B write)

  f32x4 acc[4][2] = {};
  short8 ra[4];
  float4 rb[4];

  // prologue: load + stage K-tile 0
  #pragma unroll
  for (int c = 0; c < 4; ++c){
    int gr = row0 + c * 32 + arow; if (gr > M - 1) gr = M - 1;
    ra[c] = *(const short8*)&A[(size_t)gr * 2048 + kbase + acol];
    rb[c] = *(const float4*)&W[(size_t)(n0 + c * 16 + brow) * 2048 + kbase + bcol];
  }
  #pragma unroll
  for (int c = 0; c < 4; ++c){
    *(short8*)&As[(c * 32 + arow) * LDP + acol] = ra[c];
    *(s16x4*)&Bs[(c * 16 + brow) * LDP + bcol] = cvt4(rb[c]);
  }
  __syncthreads();

  for (int t = 0; t < nsteps; ++t){
    const bool pf = (t + 1) < nsteps;
    if (pf){
      const int k0 = kbase + (t + 1) * 64;
      #pragma unroll
      for (int c = 0; c < 4; ++c){
        int gr = row0 + c * 32 + arow; if (gr > M - 1) gr = M - 1;
        ra[c] = *(const short8*)&A[(size_t)gr * 2048 + k0 + acol];
        rb[c] = *(const float4*)&W[(size_t)(n0 + c * 16 + brow) * 2048 + k0 + bcol];
      }
    }
    #pragma unroll
    for (int ks = 0; ks < 2; ++ks){
      short8 av[4], bv[2];
      #pragma unroll
      for (int f = 0; f < 4; ++f)
        av[f] = *(const short8*)&As[(wr * 64 + f * 16 + (lane & 15)) * LDP + ks * 32 + (lane >> 4) * 8];
      #pragma unroll
      for (int n = 0; n < 2; ++n)
        bv[n] = *(const short8*)&Bs[(wc * 32 + n * 16 + (lane & 15)) * LDP + ks * 32 + (lane >> 4) * 8];
      #pragma unroll
      for (int f = 0; f < 4; ++f)
        #pragma unroll
        for (int n = 0; n < 2; ++n)
          acc[f][n] = __builtin_amdgcn_mfma_f32_16x16x32_bf16(av[f], bv[n], acc[f][n], 0, 0, 0);
    }
    __syncthreads();
    if (pf){
      #pragma unroll
      for (int c = 0; c < 4; ++c){
        *(short8*)&As[(c * 32 + arow) * LDP + acol] = ra[c];
        *(s16x4*)&Bs[(c * 16 + brow) * LDP + bcol] = cvt4(rb[c]);
      }
      __syncthreads();
    }
  }

  // epilogue: C/D layout col=lane&15, row=(lane>>4)*4+reg; plain f32 stores
  #pragma unroll
  for (int f = 0; f < 4; ++f){
    #pragma unroll
    for (int n = 0; n < 2; ++n){
      const int col = n0 + wc * 32 + n * 16 + (lane & 15);
      #pragma unroll
      for (int r = 0; r < 4; ++r){
        const int row = row0 + wr * 64 + f * 16 + (lane >> 4) * 4 + r;
        if (row < M)
          Cp[(size_t)row * 2048 + col] = acc[f][n][r];
      }
    }
  }
}

__global__ __launch_bounds__(256, 4) void qkv_kernel(
    const unsigned short* __restrict__ Aq, const unsigned short* __restrict__ Awx,
    const float* __restrict__ Wq, const float* __restrict__ Wk, const float* __restrict__ Wv,
    float* __restrict__ Qp, float* __restrict__ Kp, float* __restrict__ Vp)
{
  __shared__ __align__(16) unsigned short As[128 * LDP];
  __shared__ __align__(16) unsigned short Bs[64 * LDP];
  const int nt = blockIdx.x, gy = blockIdx.y, ksp = blockIdx.z;
  if (gy == 0){
    if (ksp >= 2) return;   // Q: 2 slices of K=1024 (16 steps)
    gemm_body(Aq, Wq, Qp + (size_t)ksp * QP_STRIDE,
              128, 0, nt * 64, ksp * 1024, 16, As, Bs);
  } else if (gy < 5){
    gemm_body(Awx, Wk, Kp + (size_t)ksp * KV_STRIDE,
              512, (gy - 1) * 128, nt * 64, ksp * 512, 8, As, Bs);
  } else {
    gemm_body(Awx, Wv, Vp + (size_t)ksp * KV_STRIDE,
              512, (gy - 5) * 128, nt * 64, ksp * 512, 8, As, Bs);
  }
}

__global__ __launch_bounds__(256, 4) void o_kernel(
    const unsigned short* __restrict__ Ao, const float* __restrict__ Wo,
    float* __restrict__ Yop)
{
  __shared__ __align__(16) unsigned short As[128 * LDP];
  __shared__ __align__(16) unsigned short Bs[64 * LDP];
  gemm_body(Ao, Wo, Yop + (size_t)blockIdx.z * YO_STRIDE,
            132, blockIdx.y * 128, blockIdx.x * 64, blockIdx.z * 512, 8, As, Bs);
}

// ---------------- attention: chunks 992..1023 only, per (b,h) block ----------------
// Sums the split-K partials of Q (2) and K/V (4) during staging.
__global__ __launch_bounds__(256) void attn_kernel(
    const float* __restrict__ Qp, const float* __restrict__ Kp,
    const float* __restrict__ Vp, const int* __restrict__ amask,
    unsigned short* __restrict__ Ao)
{
  const int b = blockIdx.x >> 4;
  const int h = blockIdx.x & 15;
  __shared__ float Qs[32][129];
  __shared__ unsigned int Ks[128][65];
  __shared__ unsigned int Vs[128][65];
  __shared__ float Wt[32][132];
  __shared__ float msk[128];
  const int tid = threadIdx.x;

  for (int i = tid; i < 32 * 128; i += 256){
    int cq = i >> 7, d = i & 127;
    size_t off = (size_t)(b * 32 + cq) * 2048 + h * 128 + d;
    Qs[cq][d] = Qp[off] + Qp[off + QP_STRIDE];
  }
  for (int i = tid; i < 128 * 64; i += 256){
    int j = i >> 6, du = i & 63;
    size_t off = (size_t)(b * 128 + j) * 2048 + h * 128 + du * 2;
    float2 k0 = *(const float2*)(Kp + off);
    float2 k1 = *(const float2*)(Kp + off + KV_STRIDE);
    float2 k2 = *(const float2*)(Kp + off + 2 * KV_STRIDE);
    float2 k3 = *(const float2*)(Kp + off + 3 * KV_STRIDE);
    float2 v0 = *(const float2*)(Vp + off);
    float2 v1 = *(const float2*)(Vp + off + KV_STRIDE);
    float2 v2 = *(const float2*)(Vp + off + 2 * KV_STRIDE);
    float2 v3 = *(const float2*)(Vp + off + 3 * KV_STRIDE);
    Ks[j][du] = pk2(k0.x + k1.x + k2.x + k3.x, k0.y + k1.y + k2.y + k3.y);
    Vs[j][du] = pk2(v0.x + v1.x + v2.x + v3.x, v0.y + v1.y + v2.y + v3.y);
  }
  if (tid < 128){
    msk[tid] = (amask[b * 4096 + 3968 + tid] != 0) ? 1.f : 0.f;
    // Ao base row (chunks 0..991 collapse to v[:,0,:]); mask[b,3968]==1 here
    size_t off = (size_t)(b * 128) * 2048 + h * 128 + tid;
    Ao[(size_t)(b * 33) * 2048 + h * 128 + tid] =
        f2bf(Vp[off] + Vp[off + KV_STRIDE] + Vp[off + 2 * KV_STRIDE] + Vp[off + 3 * KV_STRIDE]);
  }
  __syncthreads();

  const int cq = tid >> 3, jg = tid & 7;
  const int jmax = 4 * cq + 3;   // causal: j <= 4*cq+3 for chunk 992+cq
  const float scale = 0.088388347648318447f; // 1/sqrt(128)

  float s[16];
  {
    float sacc[16];
    #pragma unroll
    for (int jj = 0; jj < 16; ++jj) sacc[jj] = 0.f;
    for (int du = 0; du < 64; ++du){
      float q0 = Qs[cq][2 * du], q1 = Qs[cq][2 * du + 1];
      #pragma unroll
      for (int jj = 0; jj < 16; ++jj){
        unsigned int u = Ks[jg * 16 + jj][du];
        sacc[jj] += q0 * __uint_as_float(u << 16) + q1 * __uint_as_float(u & 0xffff0000u);
      }
    }
    #pragma unroll
    for (int jj = 0; jj < 16; ++jj){
      int j = jg * 16 + jj;
      bool ok = (j <= jmax) && (msk[j] > 0.5f);
      s[jj] = ok ? sacc[jj] * scale : -1e9f;
    }
  }
  float m = s[0];
  #pragma unroll
  for (int jj = 1; jj < 16; ++jj) m = fmaxf(m, s[jj]);
  #pragma unroll
  for (int off = 1; off < 8; off <<= 1) m = fmaxf(m, __shfl_xor(m, off, 8));
  float sum = 0.f;
  #pragma unroll
  for (int jj = 0; jj < 16; ++jj){ s[jj] = expf(s[jj] - m); sum += s[jj]; }
  #pragma unroll
  for (int off = 1; off < 8; off <<= 1) sum += __shfl_xor(sum, off, 8);
  const float inv = 1.f / sum;
  #pragma unroll
  for (int jj = 0; jj < 16; ++jj) Wt[cq][jg * 16 + jj] = s[jj] * inv;
  __syncthreads();

  const int dg = tid & 7;
  float o[16];
  #pragma unroll
  for (int e = 0; e < 16; ++e) o[e] = 0.f;
  for (int j = 0; j < 128; ++j){
    float w = Wt[cq][j];
    #pragma unroll
    for (int du = 0; du < 8; ++du){
      unsigned int u = Vs[j][dg * 8 + du];
      o[2 * du]     += w * __uint_as_float(u << 16);
      o[2 * du + 1] += w * __uint_as_float(u & 0xffff0000u);
    }
  }
  unsigned short* dst = Ao + (size_t)(b * 33 + 1 + cq) * 2048 + h * 128 + dg * 16;
  #pragma unroll
  for (int e = 0; e < 16; ++e) dst[e] = f2bf(o[e]);
}

// -------- resize: sum Yo partials, linear upsample Cs=1024 -> S=4096 --------
__global__ __launch_bounds__(256) void resize_kernel(
    const float* __restrict__ Yop, float* __restrict__ out)
{
  const int rowid = blockIdx.x;       // b*4096 + i
  const int b = rowid >> 12;
  const int i = rowid & 4095;
  float c  = i * 0.25f - 0.375f;
  float fl = floorf(c);
  int   j0 = (int)fl;
  float f  = c - fl;
  int   j1 = j0 + 1;
  j0 = max(0, min(j0, 1023));
  j1 = max(0, min(j1, 1023));
  const int ri0 = b * 33 + (j0 <= 991 ? 0 : j0 - 991);
  const int ri1 = b * 33 + (j1 <= 991 ? 0 : j1 - 991);
  const float* r0 = Yop + (size_t)ri0 * 2048;
  const float* r1 = Yop + (size_t)ri1 * 2048;
  float* op = out + (size_t)rowid * 2048;
  const int t = threadIdx.x;
  const bool same = (ri0 == ri1);
  #pragma unroll
  for (int q = 0; q < 2; ++q){
    int d = q * 1024 + t * 4;
    float4 a0 = *(const float4*)(r0 + d);
    float4 a1 = *(const float4*)(r0 + d + YO_STRIDE);
    float4 a2 = *(const float4*)(r0 + d + 2 * YO_STRIDE);
    float4 a3 = *(const float4*)(r0 + d + 3 * YO_STRIDE);
    float4 a;
    a.x = a0.x + a1.x + a2.x + a3.x;
    a.y = a0.y + a1.y + a2.y + a3.y;
    a.z = a0.z + a1.z + a2.z + a3.z;
    a.w = a0.w + a1.w + a2.w + a3.w;
    float4 o = a;
    if (!same){
      float4 b0 = *(const float4*)(r1 + d);
      float4 b1 = *(const float4*)(r1 + d + YO_STRIDE);
      float4 b2 = *(const float4*)(r1 + d + 2 * YO_STRIDE);
      float4 b3 = *(const float4*)(r1 + d + 3 * YO_STRIDE);
      float4 bb;
      bb.x = b0.x + b1.x + b2.x + b3.x;
      bb.y = b0.y + b1.y + b2.y + b3.y;
      bb.z = b0.z + b1.z + b2.z + b3.z;
      bb.w = b0.w + b1.w + b2.w + b3.w;
      o.x = a.x + f * (bb.x - a.x);
      o.y = a.y + f * (bb.y - a.y);
      o.z = a.z + f * (bb.z - a.z);
      o.w = a.w + f * (bb.w - a.w);
    }
    *(float4*)(op + d) = o;
  }
}

extern "C" void kernel_launch(void* const* d_in, const int* in_sizes, int n_in,
                              void* d_out, int out_size, void* d_ws, size_t ws_size,
                              hipStream_t stream)
{
  const float* inp   = (const float*)d_in[0];
  const int*   amask = (const int*)d_in[1];
  const float* Wq = (const float*)d_in[2];
  const float* Wk = (const float*)d_in[3];
  const float* Wv = (const float*)d_in[4];
  const float* Wo = (const float*)d_in[5];
  float* out = (float*)d_out;

  char* ws = (char*)d_ws;
  unsigned short* Aq  = (unsigned short*)(ws);             // 128 x 2048 bf16 (chunk means)
  unsigned short* Awx = (unsigned short*)(ws + 524288);    // 512 x 2048 bf16 (window rows)
  float*          Qp  = (float*)(ws + 2621440);            // 2 x [128x2048] f32 partials
  float*          Kp  = (float*)(ws + 4718592);            // 4 x [512x2048] f32 partials
  float*          Vp  = (float*)(ws + 21495808);           // 4 x [512x2048] f32 partials
  float*          Yop = (float*)(ws + 38273024);           // 4 x [132x2048] f32 partials
  unsigned short* Ao  = (unsigned short*)(ws + 42598400);  // 132 x 2048 bf16

  prep_kernel<<<dim3(512, 2), 256, 0, stream>>>(inp, Awx, Aq);
  qkv_kernel<<<dim3(32, 9, 4), 256, 0, stream>>>(Aq, Awx, Wq, Wk, Wv, Qp, Kp, Vp);
  attn_kernel<<<64, 256, 0, stream>>>(Qp, Kp, Vp, amask, Ao);
  o_kernel<<<dim3(32, 2, 4), 256, 0, stream>>>(Ao, Wo, Yop);
  resize_kernel<<<16384, 256, 0, stream>>>(Yop, out);
}